// Round 12
// baseline (1277.329 us; speedup 1.0000x reference)
//
#include <hip/hip_runtime.h>

#define S_LEN 2048
#define B_SZ  64
#define D_IN  128
#define H_SZ  128
#define G4    512   // 4*H

typedef __attribute__((ext_vector_type(4))) float     floatx4;
typedef __attribute__((ext_vector_type(8))) _Float16  half8;
typedef __attribute__((ext_vector_type(4))) _Float16  half4;
typedef __attribute__((ext_vector_type(2))) _Float16  half2_t;

// DPP quad_perm helper (VALU pipe). CTRL: xor1=0xB1, xor2=0x4E.
template<int CTRL>
__device__ __forceinline__ float qperm(float v) {
  return __int_as_float(
      __builtin_amdgcn_mov_dpp(__float_as_int(v), CTRL, 0xF, 0xF, true));
}

template<int P>
__device__ __forceinline__ half2_t h2ext(half8 v) {
  return __builtin_shufflevector(v, v, 2 * P, 2 * P + 1);
}

// Barrier draining ONLY lgkmcnt (LDS); global loads/stores stay in flight.
__device__ __forceinline__ void lds_barrier() {
  asm volatile("s_waitcnt lgkmcnt(0)\n\ts_barrier" ::: "memory");
}

// ---------------------------------------------------------------------------
// Kernel 1: gx[b][n][t] = (X·Wih^T + b)·sc(ty), f16, transposed to
// [B][512][S].  ROUND 12: the transposed layout made every store an 8B
// write at 4KB stride (worst-case coalescing; gx_gemm ~158us vs ~30us
// roofline). Fix: stage each 64-row x 256-t half-chunk in LDS ([64][280]
// f16: 280 keeps rows 16B-aligned), flush with 512B-dense segments per row
// (each thread 128B contiguous). LDS 35KB + Wl 35KB -> 2 WGs/CU; all 512
// WGs resident. sc = -log2e (i,f,o), -2log2e (g).  Grid: (S/256, B).
// ---------------------------------------------------------------------------
__global__ __launch_bounds__(256) void gx_gemm(
    const float* __restrict__ X,       // [S*B][128] (row = t*64+b)
    const float* __restrict__ Wih,     // [512][128]
    const float* __restrict__ bias,    // [512]
    _Float16* __restrict__ gx)         // [64][512][2048] f16, pre-scaled
{
  __shared__ _Float16 Wl[128][136];
  __shared__ _Float16 Ol[64][280];     // staged output: 64 n-rows x 256 t
  const int tid  = threadIdx.x;
  const int lane = tid & 63;
  const int wv   = tid >> 6;
  const int b    = blockIdx.y;
  const int T0   = blockIdx.x * 256;
  const int m    = lane & 15;
  const int q    = lane >> 4;

  const float LOG2E = 1.4426950408889634f;

  half8 afrag[4][4];
  #pragma unroll
  for (int rg = 0; rg < 4; ++rg) {
    const int t = T0 + rg * 64 + wv * 16 + m;
    const float* xrow = X + ((size_t)t * B_SZ + b) * D_IN;
    #pragma unroll
    for (int kf = 0; kf < 4; ++kf) {
      const int k0 = kf * 32 + q * 8;
      floatx4 v0 = *(const floatx4*)(xrow + k0);
      floatx4 v1 = *(const floatx4*)(xrow + k0 + 4);
      half8 a;
      a[0] = (_Float16)v0.x; a[1] = (_Float16)v0.y;
      a[2] = (_Float16)v0.z; a[3] = (_Float16)v0.w;
      a[4] = (_Float16)v1.x; a[5] = (_Float16)v1.y;
      a[6] = (_Float16)v1.z; a[7] = (_Float16)v1.w;
      afrag[rg][kf] = a;
    }
  }

  for (int nc = 0; nc < 4; ++nc) {
    const float sc = (nc == 2) ? (-2.0f * LOG2E) : (-LOG2E);
    __syncthreads();
    for (int i = tid; i < 128 * 32; i += 256) {
      const int row = i >> 5;
      const int c4  = (i & 31) * 4;
      floatx4 v = *(const floatx4*)(Wih + ((size_t)nc * 128 + row) * D_IN + c4);
      Wl[row][c4 + 0] = (_Float16)v.x;
      Wl[row][c4 + 1] = (_Float16)v.y;
      Wl[row][c4 + 2] = (_Float16)v.z;
      Wl[row][c4 + 3] = (_Float16)v.w;
    }
    __syncthreads();

    #pragma unroll
    for (int half = 0; half < 2; ++half) {
      #pragma unroll
      for (int ntl = 0; ntl < 4; ++ntl) {
        const int nt  = half * 4 + ntl;
        const int n0  = nc * 128 + nt * 16;
        const int nlo = nt * 16 + m;
        const float bv = bias[n0 + m];
        half8 bfrag[4];
        #pragma unroll
        for (int kf = 0; kf < 4; ++kf)
          bfrag[kf] = *(const half8*)(&Wl[nlo][kf * 32 + q * 8]);
        #pragma unroll
        for (int rg = 0; rg < 4; ++rg) {
          floatx4 acc = {bv, bv, bv, bv};
          #pragma unroll
          for (int kf = 0; kf < 4; ++kf)
            acc = __builtin_amdgcn_mfma_f32_16x16x32_f16(afrag[rg][kf],
                                                         bfrag[kf], acc, 0, 0, 0);
          // C layout: n-offset = lane&15, t-offset = q*4 + reg
          const int tloc = rg * 64 + wv * 16 + q * 4;   // t within 256-block
          const int rloc = ntl * 16 + m;                // row within half
          half4 hv;
          hv[0] = (_Float16)(acc[0] * sc);
          hv[1] = (_Float16)(acc[1] * sc);
          hv[2] = (_Float16)(acc[2] * sc);
          hv[3] = (_Float16)(acc[3] * sc);
          *(half4*)&Ol[rloc][tloc] = hv;
        }
      }
      __syncthreads();
      // Coalesced flush: thread -> row = tid>>2 (64 rows), seg = tid&3.
      // Each thread writes 64 t = 128B contiguous; each row 512B dense.
      {
        const int row  = tid >> 2;
        const int seg  = tid & 3;
        const int nrow = nc * 128 + half * 64 + row;
        _Float16* gdst =
            gx + ((size_t)b * G4 + nrow) * S_LEN + T0 + seg * 64;
        const _Float16* lsrc = &Ol[row][seg * 64];
        #pragma unroll
        for (int i = 0; i < 8; ++i)
          *(half8*)(gdst + i * 8) = *(const half8*)(lsrc + i * 8);
      }
      __syncthreads();
    }
  }
}

// ---------------------------------------------------------------------------
// Kernel 2: reverse-time recurrence — UNCHANGED from Round 11 (best
// measured: 1113us). Structural floor established: R4/R5/R6/R8/R11 (VGPR
// 64..132, 4-8 waves, instruction mixes +/-40%) all converge to
// 1300-1390 cy/substep; residual is LDS round-trip + 8-wave barrier skew.
// types: 0=i 1=f 2=g 3=o
// ---------------------------------------------------------------------------
__device__ __forceinline__ float fd(half2_t a, half2_t b, float c) {
  return __builtin_amdgcn_fdot2(a, b, c, false);
}

__device__ __forceinline__ half8 wcvt(const float* __restrict__ p, float sc) {
  floatx4 v0 = *(const floatx4*)p;
  floatx4 v1 = *(const floatx4*)(p + 4);
  half8 h;
  h[0] = (_Float16)(v0.x * sc); h[1] = (_Float16)(v0.y * sc);
  h[2] = (_Float16)(v0.z * sc); h[3] = (_Float16)(v0.w * sc);
  h[4] = (_Float16)(v1.x * sc); h[5] = (_Float16)(v1.y * sc);
  h[6] = (_Float16)(v1.z * sc); h[7] = (_Float16)(v1.w * sc);
  return h;
}

#define PIN_WEIGHTS()                                                         \
  asm volatile(""                                                             \
               : "+v"(w00), "+v"(w01), "+v"(w02), "+v"(w03),                  \
                 "+v"(w10), "+v"(w11), "+v"(w12), "+v"(w13),                  \
                 "+v"(w20), "+v"(w21), "+v"(w22), "+v"(w23),                  \
                 "+v"(w30), "+v"(w31), "+v"(w32), "+v"(w33),                  \
                 "+v"(wt), "+v"(bt))

#define DOT8(HV, WA, WB, WC, WD)                                              \
  {                                                                           \
    q0a = fd(h2ext<0>(HV), h2ext<0>(WA), q0a);                                \
    q1a = fd(h2ext<0>(HV), h2ext<0>(WB), q1a);                                \
    q2a = fd(h2ext<0>(HV), h2ext<0>(WC), q2a);                                \
    q3a = fd(h2ext<0>(HV), h2ext<0>(WD), q3a);                                \
    q0a = fd(h2ext<1>(HV), h2ext<1>(WA), q0a);                                \
    q1a = fd(h2ext<1>(HV), h2ext<1>(WB), q1a);                                \
    q2a = fd(h2ext<1>(HV), h2ext<1>(WC), q2a);                                \
    q3a = fd(h2ext<1>(HV), h2ext<1>(WD), q3a);                                \
    q0b = fd(h2ext<2>(HV), h2ext<2>(WA), q0b);                                \
    q1b = fd(h2ext<2>(HV), h2ext<2>(WB), q1b);                                \
    q2b = fd(h2ext<2>(HV), h2ext<2>(WC), q2b);                                \
    q3b = fd(h2ext<2>(HV), h2ext<2>(WD), q3b);                                \
    q0b = fd(h2ext<3>(HV), h2ext<3>(WA), q0b);                                \
    q1b = fd(h2ext<3>(HV), h2ext<3>(WB), q1b);                                \
    q2b = fd(h2ext<3>(HV), h2ext<3>(WC), q2b);                                \
    q3b = fd(h2ext<3>(HV), h2ext<3>(WD), q3b);                                \
  }

#define GATE(HR, GXV, TMV, CVAR, HVAR)                                        \
  {                                                                           \
    half8 hv0 = *(const half8*)((HR) + 0 * 32 + tt * 8);                      \
    half8 hv1 = *(const half8*)((HR) + 1 * 32 + tt * 8);                      \
    half8 hv2 = *(const half8*)((HR) + 2 * 32 + tt * 8);                      \
    half8 hv3 = *(const half8*)((HR) + 3 * 32 + tt * 8);                      \
    asm volatile("" : "+v"(hv0), "+v"(hv1), "+v"(hv2), "+v"(hv3));            \
    float q0a = 0.f, q0b = 0.f, q1a = 0.f, q1b = 0.f;                         \
    float q2a = 0.f, q2b = 0.f, q3a = 0.f, q3b = 0.f;                         \
    PIN_WEIGHTS();                                                            \
    DOT8(hv0, w00, w10, w20, w30);                                            \
    PIN_WEIGHTS();                                                            \
    DOT8(hv1, w01, w11, w21, w31);                                            \
    PIN_WEIGHTS();                                                            \
    DOT8(hv2, w02, w12, w22, w32);                                            \
    PIN_WEIGHTS();                                                            \
    DOT8(hv3, w03, w13, w23, w33);                                            \
    float a0 = q0a + q0b, a1 = q1a + q1b, a2 = q2a + q2b, a3 = q3a + q3b;     \
    a0 += qperm<0xB1>(a0); a1 += qperm<0xB1>(a1);                             \
    a2 += qperm<0xB1>(a2); a3 += qperm<0xB1>(a3);                             \
    a0 += qperm<0x4E>(a0); a1 += qperm<0x4E>(a1);                             \
    a2 += qperm<0x4E>(a2); a3 += qperm<0x4E>(a3);                             \
    float pre = (tt & 1) ? ((tt & 2) ? a3 : a1) : ((tt & 2) ? a2 : a0);       \
    pre += (GXV);  /* already scaled by -log2e (or -2log2e for g) */          \
    const float e  = __builtin_amdgcn_exp2f(pre);                             \
    const float v  = fmaf(am, __builtin_amdgcn_rcpf(1.0f + e), aa);           \
    float z = fmaf((TMV), wt, bt);           /* = -log2e*(t*w_t+b_t) */       \
    z = fminf(z, 0.0f);                      /* -log2e*relu(.) */             \
    const float d  = __builtin_amdgcn_exp2f(z);                               \
    const float p2 = qperm<0x4E>(v);                                          \
    const float fv = (tt == 1) ? v : p2;                                      \
    const float r  = odd ? fv * (d * (CVAR)) : v * p2;                        \
    const float cn = r + qperm<0xB1>(r);                                      \
    (CVAR) = cn;                                                              \
    const float e2 = __builtin_amdgcn_exp2f(-2.0f * LOG2E * cn);              \
    const float th = fmaf(2.0f, __builtin_amdgcn_rcpf(1.0f + e2), -1.0f);     \
    (HVAR) = v * th;                                                          \
  }

#define SUB(K, TMV, RP, WP)                                                   \
  {                                                                           \
    const float g0 = (float)cur8[K];                                          \
    float h0;                                                                 \
    GATE(&hbuf[RP][0], g0, (TMV), c, h0);                                     \
    if (tt == 3) {                                                            \
      hbuf[WP][col] = (_Float16)h0;                                           \
      const int tcur = blk * 8 + K;                                           \
      out[((size_t)tcur << 13) + bH + col] = h0;                              \
      if (tcur == 0) {                                                        \
        float* hf = out + (size_t)S_LEN * B_SZ * H_SZ;                        \
        hf[bH + col] = h0;                                                    \
        hf[(size_t)B_SZ * H_SZ + bH + col] = c;                               \
      }                                                                       \
    }                                                                         \
    lds_barrier();                                                            \
  }

__global__ __launch_bounds__(512)
__attribute__((amdgpu_waves_per_eu(2, 2)))
void lstm_rev(
    const _Float16* __restrict__ gx,        // [64][512][2048] f16, pre-scaled
    const float* __restrict__ timep,        // [S*B]
    const float* __restrict__ Whh,          // [512][128]
    const float* __restrict__ w_tp,         // [128]
    const float* __restrict__ b_tp,         // [128]
    float* __restrict__ out)                // S*B*H outputs, then h, then c
{
  __shared__ __align__(16) _Float16 hbuf[2][H_SZ];   // ping-pong prev-h
  __shared__ __align__(16) float    tml[S_LEN];      // staged timep[.,b] 8KB
  const int tid = threadIdx.x;
  const int b   = blockIdx.x;                // one batch per WG
  const int tt  = tid & 3;
  const int col = tid >> 2;
  const int j   = tt * 128 + col;

  const float LOG2E = 1.4426950408889634f;

  // Stage this batch's time column into LDS (one-time, 4 loads/thread).
  #pragma unroll
  for (int k = 0; k < 4; ++k) {
    const int idx = tid + k * 512;
    tml[idx] = timep[(idx << 6) + b];
  }

  // Pre-scaled f16 weights in 16 NAMED registers: wTI = sc(T) *
  // W_hh[T*128+col][I*32+tt*8 .. +7].
  half8 w00, w01, w02, w03, w10, w11, w12, w13;
  half8 w20, w21, w22, w23, w30, w31, w32, w33;
  {
    const float s1 = -LOG2E, s2 = -2.0f * LOG2E;
    const float* r0 = Whh + (size_t)(0 * 128 + col) * H_SZ + tt * 8;
    const float* r1 = Whh + (size_t)(1 * 128 + col) * H_SZ + tt * 8;
    const float* r2 = Whh + (size_t)(2 * 128 + col) * H_SZ + tt * 8;
    const float* r3 = Whh + (size_t)(3 * 128 + col) * H_SZ + tt * 8;
    w00 = wcvt(r0 +  0, s1); w01 = wcvt(r0 + 32, s1);
    w02 = wcvt(r0 + 64, s1); w03 = wcvt(r0 + 96, s1);
    w10 = wcvt(r1 +  0, s1); w11 = wcvt(r1 + 32, s1);
    w12 = wcvt(r1 + 64, s1); w13 = wcvt(r1 + 96, s1);
    w20 = wcvt(r2 +  0, s2); w21 = wcvt(r2 + 32, s2);
    w22 = wcvt(r2 + 64, s2); w23 = wcvt(r2 + 96, s2);
    w30 = wcvt(r3 +  0, s1); w31 = wcvt(r3 + 32, s1);
    w32 = wcvt(r3 + 64, s1); w33 = wcvt(r3 + 96, s1);
  }

  float wt = -LOG2E * w_tp[col];
  float bt = -LOG2E * b_tp[col];
  const float am  = (tt == 2) ? 2.0f : 1.0f;
  const float aa  = (tt == 2) ? -1.0f : 0.0f;
  const bool  odd = (tt & 1) != 0;

  if (tid < 2 * H_SZ) ((_Float16*)hbuf)[tid] = (_Float16)0.0f;
  __syncthreads();

  // This thread's gate-x row (transposed layout): 2048 consecutive f16.
  const _Float16* gxr = gx + ((size_t)b * G4 + j) * S_LEN;
  const size_t bH = (size_t)b * H_SZ;

  // Double-buffered half8 blocks, 2 blocks (~16 substeps) ahead of use.
  half8 cur8 = *(const half8*)(gxr + 255 * 8);
  half8 nxt8 = *(const half8*)(gxr + 254 * 8);

  float c = 0.0f;

  for (int blk = 255; blk >= 0; --blk) {
    PIN_WEIGHTS();
    const int pfb = (blk >= 2) ? blk - 2 : 0;
    half8 fut8 = *(const half8*)(gxr + pfb * 8);
    const floatx4 tmA = *(const floatx4*)(&tml[blk * 8 + 4]); // t = +4..+7
    const floatx4 tmB = *(const floatx4*)(&tml[blk * 8 + 0]); // t = +0..+3

    // 8 substeps: t = blk*8+7 down to blk*8 (ping-pong parity returns to 0)
    SUB(7, tmA.w, 0, 1)
    SUB(6, tmA.z, 1, 0)
    SUB(5, tmA.y, 0, 1)
    SUB(4, tmA.x, 1, 0)
    SUB(3, tmB.w, 0, 1)
    SUB(2, tmB.z, 1, 0)
    SUB(1, tmB.y, 0, 1)
    SUB(0, tmB.x, 1, 0)

    cur8 = nxt8;
    nxt8 = fut8;
  }
}

// ---------------------------------------------------------------------------
extern "C" void kernel_launch(void* const* d_in, const int* in_sizes, int n_in,
                              void* d_out, int out_size, void* d_ws, size_t ws_size,
                              hipStream_t stream) {
  const float* input = (const float*)d_in[0];   // (S,B,D)
  const float* timep = (const float*)d_in[1];   // (S,B,1)
  const float* W_ih  = (const float*)d_in[2];   // (4H,D)
  const float* W_hh  = (const float*)d_in[3];   // (4H,H)
  const float* bias  = (const float*)d_in[4];   // (4H,)
  const float* w_t   = (const float*)d_in[5];   // (H,)
  const float* b_t   = (const float*)d_in[6];   // (H,)
  float* out = (float*)d_out;

  _Float16* gx = (_Float16*)d_ws;   // 64*512*2048*2 = 128 MiB, [b][n][t]

  gx_gemm<<<dim3(S_LEN / 256, B_SZ), dim3(256), 0, stream>>>(
      input, W_ih, bias, gx);

  lstm_rev<<<dim3(B_SZ), dim3(512), 0, stream>>>(
      gx, timep, W_hh, w_t, b_t, out);
}